// Round 7
// baseline (115.574 us; speedup 1.0000x reference)
//
#include <hip/hip_runtime.h>
#include <math.h>

// Problem constants (match reference)
#define B_SZ   4096
#define NMAX_SZ 64
#define H_SZ   768      // = 3 chunks of 256 floats; lane owns 4 floats per chunk
#define Q_SZ   16384
#define S_SZ   256

// ---------------------------------------------------------------------------
// helpers
// ---------------------------------------------------------------------------
__device__ __forceinline__ float dot12(const float4 a0, const float4 a1, const float4 a2,
                                       const float4 b0, const float4 b1, const float4 b2) {
  float p = a0.x * b0.x + a0.y * b0.y + a0.z * b0.z + a0.w * b0.w;
  p += a1.x * b1.x + a1.y * b1.y + a1.z * b1.z + a1.w * b1.w;
  p += a2.x * b2.x + a2.y * b2.y + a2.z * b2.z + a2.w * b2.w;
  return p;
}

// ---------------------------------------------------------------------------
// Kernel 1: fused attention-pool. One block per b (4096 blocks, 4x resident
// capacity -> HW backfill). NO-MAX softmax: scores s = padded_row . qw are
// bounded (qw ~ 0.02*N(0,1), H=768 -> sigma~0.55, |s|max ~ 2.8 over all
// 262k rows), so exp(s) in fp32 needs no max shift (the reference's shift
// and qb cancel in softmax identically). Inner loop is pure independent
// accumulation: l += e, a += e*x  -- no loop-carried recurrence beyond
// 1-fma accumulator adds -> maximal pipelining.
// SEQUENTIAL CHUNKS: wave w owns contiguous rows [len*w/4, len*(w+1)/4)
// -> each wave is one perfectly sequential DRAM stream (page-hit friendly),
// vs the previous stride-4 interleave.
// Coalesced chunked lane ownership (lane l owns floats 4l..4l+3 of each
// 256-float chunk): every load is a 1 KB contiguous wave burst.
// Cross-wave merge: plain sums in LDS + one __syncthreads; wave 0 epilogue
// computes d1[b]=emb.wm_w[:H], d2[b]=emb.wm_w[H:].
// ---------------------------------------------------------------------------
__global__ __launch_bounds__(256, 4) void merge_dots_kernel(
    const float* __restrict__ padded, const float* __restrict__ qw,
    const float* __restrict__ qb, const float* __restrict__ wmw,
    const int* __restrict__ lengths,
    float* __restrict__ d1, float* __restrict__ d2) {
  const int b = blockIdx.x;
  const int t = threadIdx.x;
  const int lane = t & 63;
  const int w = t >> 6;
  const int len = lengths[b];
  const int o0 = 4 * lane;        // chunk 0 offset
  const int o1 = 256 + 4 * lane;  // chunk 1 offset
  const int o2 = 512 + 4 * lane;  // chunk 2 offset
  const float LOG2E = 1.4426950408889634f;

  __shared__ float sl[4];
  __shared__ float sa[12 * 4 * 64];  // [i][w][lane], 12 KB, conflict-free

  // qw pre-scaled by log2e -> scores in base-2 domain (qb cancels in softmax)
  float4 q0 = *(const float4*)(qw + o0);
  float4 q1 = *(const float4*)(qw + o1);
  float4 q2 = *(const float4*)(qw + o2);
  q0.x *= LOG2E; q0.y *= LOG2E; q0.z *= LOG2E; q0.w *= LOG2E;
  q1.x *= LOG2E; q1.y *= LOG2E; q1.z *= LOG2E; q1.w *= LOG2E;
  q2.x *= LOG2E; q2.y *= LOG2E; q2.z *= LOG2E; q2.w *= LOG2E;

  // wave w's contiguous row range [lo, hi) -- exact partition of [0, len)
  const int lo = (len * w) >> 2;
  const int hi = (len * (w + 1)) >> 2;
  const int cnt = hi - lo;
  const float* wbase = padded + (size_t)b * (NMAX_SZ * H_SZ) + (size_t)lo * H_SZ;

  // wave-partial plain-sum state (unnormalized softmax numerator/denominator)
  float l = 0.f;
  float4 a0 = {0, 0, 0, 0}, a1 = {0, 0, 0, 0}, a2 = {0, 0, 0, 0};

  if (cnt > 0) {
    // current pair (k=0 valid; k=1 clamped if cnt==1)
    const float* rA = wbase;
    const float* rB = wbase + (size_t)((1 < cnt) ? 1 : 0) * H_SZ;
    float4 xA0 = *(const float4*)(rA + o0);
    float4 xA1 = *(const float4*)(rA + o1);
    float4 xA2 = *(const float4*)(rA + o2);
    float4 xB0 = *(const float4*)(rB + o0);
    float4 xB1 = *(const float4*)(rB + o1);
    float4 xB2 = *(const float4*)(rB + o2);

    for (int k = 0; k < cnt; k += 2) {
      // prefetch next pair (clamped; tail re-reads hit L1)
      const int pA = (k + 2 < cnt) ? k + 2 : cnt - 1;
      const int pB = (k + 3 < cnt) ? k + 3 : cnt - 1;
      const float* fA = wbase + (size_t)pA * H_SZ;
      const float* fB = wbase + (size_t)pB * H_SZ;
      const float4 nA0 = *(const float4*)(fA + o0);
      const float4 nA1 = *(const float4*)(fA + o1);
      const float4 nA2 = *(const float4*)(fA + o2);
      const float4 nB0 = *(const float4*)(fB + o0);
      const float4 nB1 = *(const float4*)(fB + o1);
      const float4 nB2 = *(const float4*)(fB + o2);

      // two independent reduce chains, interleaved (pipelined)
      float pa = dot12(xA0, xA1, xA2, q0, q1, q2);
      float pb = dot12(xB0, xB1, xB2, q0, q1, q2);
#pragma unroll
      for (int off = 32; off > 0; off >>= 1) {
        pa += __shfl_xor(pa, off);
        pb += __shfl_xor(pb, off);
      }

      const float eA = exp2f(pa);
      const float eB = (k + 1 < cnt) ? exp2f(pb) : 0.f;  // invalid row -> 0
      l += eA + eB;
      a0.x = fmaf(eA, xA0.x, fmaf(eB, xB0.x, a0.x));
      a0.y = fmaf(eA, xA0.y, fmaf(eB, xB0.y, a0.y));
      a0.z = fmaf(eA, xA0.z, fmaf(eB, xB0.z, a0.z));
      a0.w = fmaf(eA, xA0.w, fmaf(eB, xB0.w, a0.w));
      a1.x = fmaf(eA, xA1.x, fmaf(eB, xB1.x, a1.x));
      a1.y = fmaf(eA, xA1.y, fmaf(eB, xB1.y, a1.y));
      a1.z = fmaf(eA, xA1.z, fmaf(eB, xB1.z, a1.z));
      a1.w = fmaf(eA, xA1.w, fmaf(eB, xB1.w, a1.w));
      a2.x = fmaf(eA, xA2.x, fmaf(eB, xB2.x, a2.x));
      a2.y = fmaf(eA, xA2.y, fmaf(eB, xB2.y, a2.y));
      a2.z = fmaf(eA, xA2.z, fmaf(eB, xB2.z, a2.z));
      a2.w = fmaf(eA, xA2.w, fmaf(eB, xB2.w, a2.w));

      xA0 = nA0; xA1 = nA1; xA2 = nA2;
      xB0 = nB0; xB1 = nB1; xB2 = nB2;
    }
  }

  // publish wave-partial sums to LDS (transposed: sa[i*256 + w*64 + lane])
  if (lane == 0) sl[w] = l;
  if (w != 0) {  // wave 0 keeps its state in registers
    const float av[12] = {a0.x, a0.y, a0.z, a0.w, a1.x, a1.y, a1.z, a1.w,
                          a2.x, a2.y, a2.z, a2.w};
#pragma unroll
    for (int i = 0; i < 12; ++i) sa[i * 256 + w * 64 + lane] = av[i];
  }
  __syncthreads();
  if (w != 0) return;

  // wave 0: cross-wave merge = plain sums (len>=1 -> L > 0)
  const float L = sl[0] + sl[1] + sl[2] + sl[3];
  const float inv = 1.f / L;

  float e[12] = {a0.x, a0.y, a0.z, a0.w, a1.x, a1.y, a1.z, a1.w,
                 a2.x, a2.y, a2.z, a2.w};
#pragma unroll
  for (int i = 0; i < 12; ++i) {
    e[i] = (e[i] + sa[i * 256 + 64 + lane] +
            sa[i * 256 + 128 + lane] + sa[i * 256 + 192 + lane]) * inv;
  }

  // epilogue: dots with both wm_w halves (same chunked offsets)
  const float4 w10 = *(const float4*)(wmw + o0);
  const float4 w11 = *(const float4*)(wmw + o1);
  const float4 w12 = *(const float4*)(wmw + o2);
  const float4 w20 = *(const float4*)(wmw + H_SZ + o0);
  const float4 w21 = *(const float4*)(wmw + H_SZ + o1);
  const float4 w22 = *(const float4*)(wmw + H_SZ + o2);
  float p1 = e[0] * w10.x + e[1] * w10.y + e[2] * w10.z + e[3] * w10.w
           + e[4] * w11.x + e[5] * w11.y + e[6] * w11.z + e[7] * w11.w
           + e[8] * w12.x + e[9] * w12.y + e[10] * w12.z + e[11] * w12.w;
  float p2 = e[0] * w20.x + e[1] * w20.y + e[2] * w20.z + e[3] * w20.w
           + e[4] * w21.x + e[5] * w21.y + e[6] * w21.z + e[7] * w21.w
           + e[8] * w22.x + e[9] * w22.y + e[10] * w22.z + e[11] * w22.w;
#pragma unroll
  for (int off = 32; off > 0; off >>= 1) {
    p1 += __shfl_xor(p1, off);
    p2 += __shfl_xor(p2, off);
  }
  if (lane == 0) {
    d1[b] = p1;
    d2[b] = p2;
  }
}

// ---------------------------------------------------------------------------
// Kernel 2: logits[q] = (d1[cni[npt[q]]] + d2[npi[q]] + wm_b) / TEMP ; pos flag
// ---------------------------------------------------------------------------
__global__ __launch_bounds__(256) void logits_kernel(
    const float* __restrict__ d1, const float* __restrict__ d2,
    const float* __restrict__ wmb,
    const int* __restrict__ npi, const int* __restrict__ cni,
    const int* __restrict__ npt, const int* __restrict__ labels,
    float* __restrict__ logits, int* __restrict__ pos) {
  const int q = blockIdx.x * 256 + threadIdx.x;
  if (q >= Q_SZ) return;
  const int ty = npt[q];
  const float sims = d1[cni[ty]] + d2[npi[q]] + wmb[0];
  logits[q] = sims / 0.1f;            // match reference's division by TEMP
  pos[q] = (labels[q] == 1) ? 1 : 0;  // labels is [Q,1]
}

// ---------------------------------------------------------------------------
// Kernel 3: per-segment LSE terms. One block per segment s; scans all Q
// (logits/npt/pos are L2-resident). Two passes: max, then sums.
// ---------------------------------------------------------------------------
__global__ __launch_bounds__(256) void segment_kernel(
    const float* __restrict__ logits, const int* __restrict__ npt,
    const int* __restrict__ pos,
    float* __restrict__ seg_term, float* __restrict__ seg_has) {
  const int s = blockIdx.x;
  const int t = threadIdx.x;
  const int lane = t & 63, wid = t >> 6;
  __shared__ float rg[4], rp[4], sa4[4], sp4[4], cp4[4];

  float gmax = -INFINITY, pmax = -INFINITY;
  for (int q = t; q < Q_SZ; q += 256) {
    if (npt[q] == s) {
      const float lg = logits[q];
      gmax = fmaxf(gmax, lg);
      if (pos[q]) pmax = fmaxf(pmax, lg);
    }
  }
#pragma unroll
  for (int off = 32; off > 0; off >>= 1) {
    gmax = fmaxf(gmax, __shfl_xor(gmax, off));
    pmax = fmaxf(pmax, __shfl_xor(pmax, off));
  }
  if (lane == 0) { rg[wid] = gmax; rp[wid] = pmax; }
  __syncthreads();
  gmax = fmaxf(fmaxf(rg[0], rg[1]), fmaxf(rg[2], rg[3]));
  pmax = fmaxf(fmaxf(rp[0], rp[1]), fmaxf(rp[2], rp[3]));
  const float gmaxs = (gmax == -INFINITY) ? 0.f : gmax;
  const float pmaxs = (pmax == -INFINITY) ? 0.f : pmax;

  float sa = 0.f, sp = 0.f, cnt = 0.f;
  for (int q = t; q < Q_SZ; q += 256) {
    if (npt[q] == s) {
      const float lg = logits[q];
      sa += expf(lg - gmaxs);
      if (pos[q]) { sp += expf(lg - pmaxs); cnt += 1.f; }
    }
  }
#pragma unroll
  for (int off = 32; off > 0; off >>= 1) {
    sa += __shfl_xor(sa, off);
    sp += __shfl_xor(sp, off);
    cnt += __shfl_xor(cnt, off);
  }
  if (lane == 0) { sa4[wid] = sa; sp4[wid] = sp; cp4[wid] = cnt; }
  __syncthreads();
  if (t == 0) {
    sa = sa4[0] + sa4[1] + sa4[2] + sa4[3];
    sp = sp4[0] + sp4[1] + sp4[2] + sp4[3];
    cnt = cp4[0] + cp4[1] + cp4[2] + cp4[3];
    const bool haspos = cnt > 0.f;
    float term = 0.f;
    if (haspos) term = (logf(sa) + gmaxs) - (logf(sp) + pmaxs);
    seg_term[s] = term;
    seg_has[s] = haspos ? 1.f : 0.f;
  }
}

// ---------------------------------------------------------------------------
// Kernel 4: loss = sum(term) / max(sum(has), 1)
// ---------------------------------------------------------------------------
__global__ __launch_bounds__(256) void finalize_kernel(
    const float* __restrict__ seg_term, const float* __restrict__ seg_has,
    float* __restrict__ out) {
  const int t = threadIdx.x;
  const int lane = t & 63, wid = t >> 6;
  __shared__ float rt[4], rh[4];
  float v = seg_term[t];
  float h = seg_has[t];
#pragma unroll
  for (int off = 32; off > 0; off >>= 1) {
    v += __shfl_xor(v, off);
    h += __shfl_xor(h, off);
  }
  if (lane == 0) { rt[wid] = v; rh[wid] = h; }
  __syncthreads();
  if (t == 0) {
    const float total = rt[0] + rt[1] + rt[2] + rt[3];
    const float nv = rh[0] + rh[1] + rh[2] + rh[3];
    out[0] = total / fmaxf(nv, 1.f);
  }
}

extern "C" void kernel_launch(void* const* d_in, const int* in_sizes, int n_in,
                              void* d_out, int out_size, void* d_ws, size_t ws_size,
                              hipStream_t stream) {
  const float* padded  = (const float*)d_in[0];
  const float* qw      = (const float*)d_in[1];
  const float* qb      = (const float*)d_in[2];
  const float* wmw     = (const float*)d_in[3];
  const float* wmb     = (const float*)d_in[4];
  const int*   lengths = (const int*)d_in[5];
  const int*   npi     = (const int*)d_in[6];
  const int*   cni     = (const int*)d_in[7];
  const int*   npt     = (const int*)d_in[8];
  const int*   labels  = (const int*)d_in[9];
  float* out = (float*)d_out;

  // workspace layout (all fully written before read each call)
  float* d1       = (float*)d_ws;          // B
  float* d2       = d1 + B_SZ;             // B
  float* logits   = d2 + B_SZ;             // Q
  int*   pos      = (int*)(logits + Q_SZ); // Q
  float* seg_term = (float*)(pos + Q_SZ);  // S
  float* seg_has  = seg_term + S_SZ;       // S

  merge_dots_kernel<<<B_SZ, 256, 0, stream>>>(padded, qw, qb, wmw, lengths, d1, d2);
  logits_kernel<<<Q_SZ / 256, 256, 0, stream>>>(d1, d2, wmb, npi, cni, npt, labels,
                                                logits, pos);
  segment_kernel<<<S_SZ, 256, 0, stream>>>(logits, npt, pos, seg_term, seg_has);
  finalize_kernel<<<1, 256, 0, stream>>>(seg_term, seg_has, out);
}

// Round 8
// 99.323 us; speedup vs baseline: 1.1636x; 1.1636x over previous
//
#include <hip/hip_runtime.h>
#include <math.h>

// Problem constants (match reference)
#define B_SZ   4096
#define NMAX_SZ 64
#define H_SZ   768      // = 3 chunks of 256 floats; lane owns 4 floats per chunk
#define Q_SZ   16384
#define S_SZ   256

typedef float f4 __attribute__((ext_vector_type(4)));

// nontemporal float4 load (streaming read-once data: skip cache fill)
__device__ __forceinline__ f4 ldnt(const float* p) {
  return __builtin_nontemporal_load((const f4*)p);
}
__device__ __forceinline__ float dot4(const f4 a, const f4 b) {
  const f4 p = a * b;
  return p[0] + p[1] + p[2] + p[3];
}

// ---------------------------------------------------------------------------
// Kernel 1: fused attention-pool. One block per b (4096 blocks, HW backfill).
// NO-MAX softmax (scores bounded: qw ~ 0.02*N(0,1), H=768 -> |s| < ~3; the
// reference's max-shift and qb cancel identically in softmax). Inner loop is
// pure independent accumulation (no loop-carried recurrence beyond 1-fma
// accumulator adds). Wave w owns contiguous rows [len*w/4, len*(w+1)/4).
// Lane l owns floats {4l..4l+3} of each 256-float chunk -> every load is a
// 1 KB contiguous wave burst. NEW: nontemporal loads on padded (read-once
// stream; avoid L2 fill/evict overhead).
// Cross-wave merge: plain sums in LDS + one __syncthreads; wave 0 epilogue
// computes d1[b]=emb.wm_w[:H], d2[b]=emb.wm_w[H:].
// ---------------------------------------------------------------------------
__global__ __launch_bounds__(256, 4) void merge_dots_kernel(
    const float* __restrict__ padded, const float* __restrict__ qw,
    const float* __restrict__ wmw, const int* __restrict__ lengths,
    float* __restrict__ d1, float* __restrict__ d2) {
  const int b = blockIdx.x;
  const int t = threadIdx.x;
  const int lane = t & 63;
  const int w = t >> 6;
  const int len = lengths[b];
  const int o0 = 4 * lane;        // chunk 0 offset
  const int o1 = 256 + 4 * lane;  // chunk 1 offset
  const int o2 = 512 + 4 * lane;  // chunk 2 offset
  const float LOG2E = 1.4426950408889634f;

  __shared__ float sl[4];
  __shared__ float sa[12 * 4 * 64];  // [i][w][lane], 12 KB, conflict-free

  // qw pre-scaled by log2e -> scores in base-2 domain (qb cancels in softmax)
  f4 q0 = *(const f4*)(qw + o0) * LOG2E;
  f4 q1 = *(const f4*)(qw + o1) * LOG2E;
  f4 q2 = *(const f4*)(qw + o2) * LOG2E;

  // wave w's contiguous row range [lo, hi) -- exact partition of [0, len)
  const int lo = (len * w) >> 2;
  const int hi = (len * (w + 1)) >> 2;
  const int cnt = hi - lo;
  const float* wbase = padded + (size_t)b * (NMAX_SZ * H_SZ) + (size_t)lo * H_SZ;

  // wave-partial plain-sum state (unnormalized softmax numerator/denominator)
  float l = 0.f;
  f4 a0 = {0, 0, 0, 0}, a1 = {0, 0, 0, 0}, a2 = {0, 0, 0, 0};

  if (cnt > 0) {
    // current pair (k=0 valid; k=1 clamped if cnt==1)
    const float* rA = wbase;
    const float* rB = wbase + (size_t)((1 < cnt) ? 1 : 0) * H_SZ;
    f4 xA0 = ldnt(rA + o0), xA1 = ldnt(rA + o1), xA2 = ldnt(rA + o2);
    f4 xB0 = ldnt(rB + o0), xB1 = ldnt(rB + o1), xB2 = ldnt(rB + o2);

    for (int k = 0; k < cnt; k += 2) {
      // prefetch next pair (clamped; tail re-reads hit cache/L2)
      const int pA = (k + 2 < cnt) ? k + 2 : cnt - 1;
      const int pB = (k + 3 < cnt) ? k + 3 : cnt - 1;
      const float* fA = wbase + (size_t)pA * H_SZ;
      const float* fB = wbase + (size_t)pB * H_SZ;
      const f4 nA0 = ldnt(fA + o0), nA1 = ldnt(fA + o1), nA2 = ldnt(fA + o2);
      const f4 nB0 = ldnt(fB + o0), nB1 = ldnt(fB + o1), nB2 = ldnt(fB + o2);

      // two independent reduce chains, interleaved (pipelined)
      float pa = dot4(xA0, q0) + dot4(xA1, q1) + dot4(xA2, q2);
      float pb = dot4(xB0, q0) + dot4(xB1, q1) + dot4(xB2, q2);
#pragma unroll
      for (int off = 32; off > 0; off >>= 1) {
        pa += __shfl_xor(pa, off);
        pb += __shfl_xor(pb, off);
      }

      const float eA = exp2f(pa);
      const float eB = (k + 1 < cnt) ? exp2f(pb) : 0.f;  // invalid row -> 0
      l += eA + eB;
      a0 += eA * xA0 + eB * xB0;
      a1 += eA * xA1 + eB * xB1;
      a2 += eA * xA2 + eB * xB2;

      xA0 = nA0; xA1 = nA1; xA2 = nA2;
      xB0 = nB0; xB1 = nB1; xB2 = nB2;
    }
  }

  // publish wave-partial sums to LDS (transposed: sa[i*256 + w*64 + lane])
  if (lane == 0) sl[w] = l;
  if (w != 0) {  // wave 0 keeps its state in registers
    const float av[12] = {a0[0], a0[1], a0[2], a0[3], a1[0], a1[1], a1[2], a1[3],
                          a2[0], a2[1], a2[2], a2[3]};
#pragma unroll
    for (int i = 0; i < 12; ++i) sa[i * 256 + w * 64 + lane] = av[i];
  }
  __syncthreads();
  if (w != 0) return;

  // wave 0: cross-wave merge = plain sums (len>=1 -> L > 0)
  const float L = sl[0] + sl[1] + sl[2] + sl[3];
  const float inv = 1.f / L;

  float e[12] = {a0[0], a0[1], a0[2], a0[3], a1[0], a1[1], a1[2], a1[3],
                 a2[0], a2[1], a2[2], a2[3]};
#pragma unroll
  for (int i = 0; i < 12; ++i) {
    e[i] = (e[i] + sa[i * 256 + 64 + lane] +
            sa[i * 256 + 128 + lane] + sa[i * 256 + 192 + lane]) * inv;
  }

  // epilogue: dots with both wm_w halves (same chunked offsets)
  const f4 w10 = *(const f4*)(wmw + o0);
  const f4 w11 = *(const f4*)(wmw + o1);
  const f4 w12 = *(const f4*)(wmw + o2);
  const f4 w20 = *(const f4*)(wmw + H_SZ + o0);
  const f4 w21 = *(const f4*)(wmw + H_SZ + o1);
  const f4 w22 = *(const f4*)(wmw + H_SZ + o2);
  float p1 = e[0] * w10[0] + e[1] * w10[1] + e[2] * w10[2] + e[3] * w10[3]
           + e[4] * w11[0] + e[5] * w11[1] + e[6] * w11[2] + e[7] * w11[3]
           + e[8] * w12[0] + e[9] * w12[1] + e[10] * w12[2] + e[11] * w12[3];
  float p2 = e[0] * w20[0] + e[1] * w20[1] + e[2] * w20[2] + e[3] * w20[3]
           + e[4] * w21[0] + e[5] * w21[1] + e[6] * w21[2] + e[7] * w21[3]
           + e[8] * w22[0] + e[9] * w22[1] + e[10] * w22[2] + e[11] * w22[3];
#pragma unroll
  for (int off = 32; off > 0; off >>= 1) {
    p1 += __shfl_xor(p1, off);
    p2 += __shfl_xor(p2, off);
  }
  if (lane == 0) {
    d1[b] = p1;
    d2[b] = p2;
  }
}

// ---------------------------------------------------------------------------
// Kernel 2 (fused logits+segment): one block per segment s. The per-segment
// source term d1[cni[s]] is block-uniform; per-query logit is computed
// inline from the L2-resident d2/npi/labels (no logits/pos round-trip, no
// separate launch, no memset). Two passes: max, then sums.
// ---------------------------------------------------------------------------
__global__ __launch_bounds__(256) void segment_kernel(
    const float* __restrict__ d1, const float* __restrict__ d2,
    const float* __restrict__ wmb,
    const int* __restrict__ npi, const int* __restrict__ cni,
    const int* __restrict__ npt, const int* __restrict__ labels,
    float* __restrict__ seg_term, float* __restrict__ seg_has) {
  const int s = blockIdx.x;
  const int t = threadIdx.x;
  const int lane = t & 63, wid = t >> 6;
  __shared__ float rg[4], rp[4], sa4[4], sp4[4], cp4[4];

  const float base = d1[cni[s]] + wmb[0];  // block-uniform source dot + bias

  float gmax = -INFINITY, pmax = -INFINITY;
  for (int q = t; q < Q_SZ; q += 256) {
    if (npt[q] == s) {
      const float lg = (base + d2[npi[q]]) * 10.f;  // /TEMP
      gmax = fmaxf(gmax, lg);
      if (labels[q] == 1) pmax = fmaxf(pmax, lg);
    }
  }
#pragma unroll
  for (int off = 32; off > 0; off >>= 1) {
    gmax = fmaxf(gmax, __shfl_xor(gmax, off));
    pmax = fmaxf(pmax, __shfl_xor(pmax, off));
  }
  if (lane == 0) { rg[wid] = gmax; rp[wid] = pmax; }
  __syncthreads();
  gmax = fmaxf(fmaxf(rg[0], rg[1]), fmaxf(rg[2], rg[3]));
  pmax = fmaxf(fmaxf(rp[0], rp[1]), fmaxf(rp[2], rp[3]));
  const float gmaxs = (gmax == -INFINITY) ? 0.f : gmax;
  const float pmaxs = (pmax == -INFINITY) ? 0.f : pmax;

  float sa = 0.f, sp = 0.f, cnt = 0.f;
  for (int q = t; q < Q_SZ; q += 256) {
    if (npt[q] == s) {
      const float lg = (base + d2[npi[q]]) * 10.f;
      sa += expf(lg - gmaxs);
      if (labels[q] == 1) { sp += expf(lg - pmaxs); cnt += 1.f; }
    }
  }
#pragma unroll
  for (int off = 32; off > 0; off >>= 1) {
    sa += __shfl_xor(sa, off);
    sp += __shfl_xor(sp, off);
    cnt += __shfl_xor(cnt, off);
  }
  if (lane == 0) { sa4[wid] = sa; sp4[wid] = sp; cp4[wid] = cnt; }
  __syncthreads();
  if (t == 0) {
    sa = sa4[0] + sa4[1] + sa4[2] + sa4[3];
    sp = sp4[0] + sp4[1] + sp4[2] + sp4[3];
    cnt = cp4[0] + cp4[1] + cp4[2] + cp4[3];
    const bool haspos = cnt > 0.f;
    float term = 0.f;
    if (haspos) term = (logf(sa) + gmaxs) - (logf(sp) + pmaxs);
    seg_term[s] = term;
    seg_has[s] = haspos ? 1.f : 0.f;
  }
}

// ---------------------------------------------------------------------------
// Kernel 3: loss = sum(term) / max(sum(has), 1)
// ---------------------------------------------------------------------------
__global__ __launch_bounds__(256) void finalize_kernel(
    const float* __restrict__ seg_term, const float* __restrict__ seg_has,
    float* __restrict__ out) {
  const int t = threadIdx.x;
  const int lane = t & 63, wid = t >> 6;
  __shared__ float rt[4], rh[4];
  float v = seg_term[t];
  float h = seg_has[t];
#pragma unroll
  for (int off = 32; off > 0; off >>= 1) {
    v += __shfl_xor(v, off);
    h += __shfl_xor(h, off);
  }
  if (lane == 0) { rt[wid] = v; rh[wid] = h; }
  __syncthreads();
  if (t == 0) {
    const float total = rt[0] + rt[1] + rt[2] + rt[3];
    const float nv = rh[0] + rh[1] + rh[2] + rh[3];
    out[0] = total / fmaxf(nv, 1.f);
  }
}

extern "C" void kernel_launch(void* const* d_in, const int* in_sizes, int n_in,
                              void* d_out, int out_size, void* d_ws, size_t ws_size,
                              hipStream_t stream) {
  const float* padded  = (const float*)d_in[0];
  const float* qw      = (const float*)d_in[1];
  // d_in[2] = qb: cancels identically in softmax -> unused
  const float* wmw     = (const float*)d_in[3];
  const float* wmb     = (const float*)d_in[4];
  const int*   lengths = (const int*)d_in[5];
  const int*   npi     = (const int*)d_in[6];
  const int*   cni     = (const int*)d_in[7];
  const int*   npt     = (const int*)d_in[8];
  const int*   labels  = (const int*)d_in[9];
  float* out = (float*)d_out;

  // workspace layout (all fully written before read each call)
  float* d1       = (float*)d_ws;          // B
  float* d2       = d1 + B_SZ;             // B
  float* seg_term = d2 + B_SZ;             // S
  float* seg_has  = seg_term + S_SZ;       // S

  merge_dots_kernel<<<B_SZ, 256, 0, stream>>>(padded, qw, wmw, lengths, d1, d2);
  segment_kernel<<<S_SZ, 256, 0, stream>>>(d1, d2, wmb, npi, cni, npt, labels,
                                           seg_term, seg_has);
  finalize_kernel<<<1, 256, 0, stream>>>(seg_term, seg_has, out);
}